// Round 5
// baseline (397.394 us; speedup 1.0000x reference)
//
#include <hip/hip_runtime.h>
#include <cmath>

// Problem constants: B=8, DIM=128, T=16, H*W=1024, INNER=256, UP2=512,
// NH=4, DH=64, K=4, Bx=8192 sequences, S=16.

typedef __attribute__((ext_vector_type(8))) short short8;
typedef __attribute__((ext_vector_type(4))) short short4v;
typedef __attribute__((ext_vector_type(4))) float f32x4;
typedef unsigned short ushort_t;

static __device__ __forceinline__ float siluf(float v) {
  return v / (1.0f + __expf(-v));
}
static __device__ __forceinline__ float logsigf(float v) {
  return fminf(v, 0.f) - log1pf(__expf(-fabsf(v)));
}
static __device__ __forceinline__ float sel4(float4 w, int idx) {
  float r = w.x;
  r = (idx == 1) ? w.y : r;
  r = (idx == 2) ? w.z : r;
  r = (idx == 3) ? w.w : r;
  return r;
}
static __device__ __forceinline__ ushort_t f2bf(float x) {   // RNE fp32->bf16
  unsigned u = __float_as_uint(x);
  return (ushort_t)((u + 0x7fffu + ((u >> 16) & 1u)) >> 16);
}
static __device__ __forceinline__ float bf2f(ushort_t h) {
  return __uint_as_float(((unsigned)h) << 16);
}

// ---------------------------------------------------------------------------
// prep_x: transpose + hi/lo split of x into xt_hi/xt_lo [131072 rows][128 c].
// row = bt*1024 + hw. Memory-bound (~128 MB traffic).
// ---------------------------------------------------------------------------
__global__ __launch_bounds__(256)
void prep_x(const float* __restrict__ x,
            ushort_t* __restrict__ xt_hi, ushort_t* __restrict__ xt_lo)
{
  const int hw = blockIdx.x * 256 + threadIdx.x;   // grid.x = 4
  const int bt = blockIdx.y;                        // 128
  const int b  = bt >> 4, t = bt & 15;
  const int row = bt * 1024 + hw;
  const float* xb = &x[(b*128*16 + t)*1024 + hw];   // + c*16*1024 per channel

  #pragma unroll
  for (int c0 = 0; c0 < 128; c0 += 8) {
    short8 hv, lv;
    #pragma unroll
    for (int ii = 0; ii < 8; ++ii) {
      const float v = xb[(c0 + ii) * 16384];
      const ushort_t h = f2bf(v);
      hv[ii] = (short)h;
      lv[ii] = (short)f2bf(v - bf2f(h));
    }
    *(short8*)&xt_hi[row*128 + c0] = hv;
    *(short8*)&xt_lo[row*128 + c0] = lv;
  }
}

// ---------------------------------------------------------------------------
// prep_w: weight fragments, FRAGMENT-MAJOR (one 1KB coalesced load per frag).
//  wtf  [j16(32)][kc(4)][hl(2)][512]: B-frag of Wup; lane ln element i holds
//        Wup[kc*32 + (ln>>4)*8 + i][j16*16 + (ln&15)]
//  wdtf [c16(8)][kc(8)][hl(2)][512]: A-frag of Wd^T; lane ln element i holds
//        Wd[kc*32 + (ln>>4)*8 + i][c16*16 + (ln&15)]
//  wgf  [24][64][8]: gate-GEMM B-frags (ig cols 0-3, fg cols 4-7, rest 0)
// ---------------------------------------------------------------------------
__global__ __launch_bounds__(256)
void prep_w(const float* __restrict__ Wup, const float* __restrict__ Wd,
            const float* __restrict__ igw, const float* __restrict__ fgw,
            ushort_t* __restrict__ wtf, ushort_t* __restrict__ wdtf,
            ushort_t* __restrict__ wgf)
{
  const int g = blockIdx.x * 256 + threadIdx.x;
  if (g < 131072) {                     // wtf
    const int i   = g & 7;
    const int ln  = (g >> 3) & 63;
    const int hl  = (g >> 9) & 1;
    const int kc  = (g >> 10) & 3;
    const int j16 = g >> 12;
    const int c = kc*32 + (ln >> 4)*8 + i;
    const int j = j16*16 + (ln & 15);
    const float w = Wup[c*512 + j];
    const ushort_t h = f2bf(w);
    wtf[g] = hl ? f2bf(w - bf2f(h)) : h;
  } else if (g < 196608) {              // wdtf
    const int e   = g - 131072;
    const int i   = e & 7;
    const int ln  = (e >> 3) & 63;
    const int hl  = (e >> 9) & 1;
    const int kc  = (e >> 10) & 7;
    const int c16 = e >> 13;
    const int m = c16*16 + (ln & 15);
    const int k = kc*32 + (ln >> 4)*8 + i;
    const float w = Wd[k*128 + m];
    const ushort_t h = f2bf(w);
    wdtf[e] = hl ? f2bf(w - bf2f(h)) : h;
  } else if (g < 208896) {              // gate fragments
    const int e = g - 196608;           // e = kc*512 + lane*8 + i
    const int kc = e >> 9;
    const int lane = (e >> 3) & 63;
    const int i = e & 7;
    const int n = lane & 15;
    const int kq = kc*32 + (lane >> 4)*8 + i;
    float val = 0.f;
    if (n < 4)      val = igw[kq*4 + n];
    else if (n < 8) val = fgw[kq*4 + (n - 4)];
    wgf[e] = f2bf(val);
  }
}

// ---------------------------------------------------------------------------
// Phase 1: up-projection via split-bf16 MFMA.
// A staged from pre-split xt (no conversion VALU), B frag-major from global,
// epilogue via LDS transpose -> coalesced 16B stores.
// ---------------------------------------------------------------------------
__global__ __launch_bounds__(256, 4)
void up_gemm(const ushort_t* __restrict__ xt_hi, const ushort_t* __restrict__ xt_lo,
             const ushort_t* __restrict__ wtf,
             ushort_t* __restrict__ xmb, ushort_t* __restrict__ szb)
{
  // staging: sAhi/sAlo 128 rows x 72 ushort (144B, 16B-aligned rows)
  // epilogue alias: 128 rows x 136 ushort (272B rows). 36,864 B total.
  __shared__ __align__(16) ushort_t ldsbuf[2*128*72];
  ushort_t* sAhi = ldsbuf;
  ushort_t* sAlo = ldsbuf + 128*72;

  const int tid = threadIdx.x;
  const int hw0 = blockIdx.x * 128;
  const int j0  = blockIdx.y * 128;
  const int bt  = blockIdx.z;
  const int rowbase = bt*1024 + hw0;

  const int wv = tid >> 6;
  const int wm = wv >> 1, wn = wv & 1;
  const int ln = tid & 63;
  const int lm = ln & 15;
  const int q  = ln >> 4;

  f32x4 acc[4][4];
  #pragma unroll
  for (int i = 0; i < 4; ++i)
    #pragma unroll
    for (int k = 0; k < 4; ++k) acc[i][k] = (f32x4){0.f, 0.f, 0.f, 0.f};

  for (int stage = 0; stage < 2; ++stage) {
    // --- stage A: 128 rows x 64 c (hi+lo), pure 16B copy ---
    #pragma unroll
    for (int p = 0; p < 4; ++p) {
      const int row = wv*32 + p*8 + (ln >> 3);
      const int ck  = (ln & 7) * 8;
      const int gidx = (rowbase + row)*128 + stage*64 + ck;
      const short8 hv = *(const short8*)&xt_hi[gidx];
      const short8 lv = *(const short8*)&xt_lo[gidx];
      *(short8*)&sAhi[row*72 + ck] = hv;
      *(short8*)&sAlo[row*72 + ck] = lv;
    }
    __syncthreads();

    #pragma unroll
    for (int s = 0; s < 2; ++s) {
      const int kc = stage*2 + s;
      // B-frags: fully coalesced 1KB/wave loads
      short8 bh[4], bl[4];
      #pragma unroll
      for (int nt = 0; nt < 4; ++nt) {
        const int j16 = (j0 >> 4) + wn*4 + nt;
        const int base = (j16*4 + kc)*1024;
        bh[nt] = *(const short8*)&wtf[base + ln*8];
        bl[nt] = *(const short8*)&wtf[base + 512 + ln*8];
      }
      const int ck = (s*4 + q)*8;
      #pragma unroll
      for (int mt = 0; mt < 4; ++mt) {
        const int ao = (wm*64 + mt*16 + lm)*72 + ck;
        const short8 ah = *(const short8*)&sAhi[ao];
        const short8 al = *(const short8*)&sAlo[ao];
        #pragma unroll
        for (int nt = 0; nt < 4; ++nt) {
          acc[mt][nt] = __builtin_amdgcn_mfma_f32_16x16x32_bf16(ah, bh[nt], acc[mt][nt], 0, 0, 0);
          acc[mt][nt] = __builtin_amdgcn_mfma_f32_16x16x32_bf16(ah, bl[nt], acc[mt][nt], 0, 0, 0);
          acc[mt][nt] = __builtin_amdgcn_mfma_f32_16x16x32_bf16(al, bh[nt], acc[mt][nt], 0, 0, 0);
        }
      }
    }
    __syncthreads();
  }

  // --- epilogue: LDS transpose -> coalesced 16B stores ---
  const bool isz = (j0 >= 256);
  ushort_t* eL = ldsbuf;          // 128 x 136 ushort
  #pragma unroll
  for (int mt = 0; mt < 4; ++mt) {
    #pragma unroll
    for (int nt = 0; nt < 4; ++nt) {
      const int col = wn*64 + nt*16 + lm;
      #pragma unroll
      for (int r = 0; r < 4; ++r) {
        const int row = wm*64 + mt*16 + q*4 + r;
        float v = acc[mt][nt][r];
        if (isz) v = siluf(v);
        eL[row*136 + col] = f2bf(v);
      }
    }
  }
  __syncthreads();
  {
    const int rq = ln >> 4, ck = ln & 15;
    #pragma unroll
    for (int p = 0; p < 8; ++p) {
      const int row = wv*32 + p*4 + rq;
      const short8 val = *(const short8*)&eL[row*136 + ck*8];
      const int rowg = rowbase + row;
      if (!isz) *(short8*)&xmb[rowg*256 + j0 + ck*8] = val;
      else      *(short8*)&szb[rowg*256 + (j0 - 256) + ck*8] = val;
    }
  }
}

// ---------------------------------------------------------------------------
// Phase 2: fused conv + qkv + gates + mLSTM + LN + skip (unchanged from R4).
// ---------------------------------------------------------------------------
#define SQ 264
#define SXC 260

__global__ __launch_bounds__(256, 4)
void seq_kernel(const ushort_t* __restrict__ xm_ws,
                ushort_t* szh,                    // silu(z) in, h_state out
                const float* __restrict__ conv_w, const float* __restrict__ conv_b,
                const float* __restrict__ Wq, const float* __restrict__ Wk,
                const float* __restrict__ Wv,
                const ushort_t* __restrict__ wgf,
                const float* __restrict__ igb, const float* __restrict__ fgb,
                const float* __restrict__ lnw, const float* __restrict__ skipw)
{
  __shared__ __align__(16) ushort_t q_lds[16*SQ];
  __shared__ __align__(16) ushort_t k_lds[16*SQ];
  __shared__ __align__(16) ushort_t v_lds[16*SQ];
  __shared__ __align__(16) ushort_t xc_lds[16*SXC];
  __shared__ __align__(16) ushort_t p_lds[4*16*36];
  __shared__ __align__(16) float s_gpart[512];
  __shared__ float s_ig[64];
  __shared__ float s_lf[64];

  const int tid = threadIdx.x;
  const int j   = tid;
  const int l2  = j & 3;
  const int seq = blockIdx.x;
  const int rbase = (seq >> 10) * 16384 + (seq & 1023);

  const int w    = tid >> 6;
  const int ln   = tid & 63;
  const int g    = ln >> 4;
  const int lc   = ln & 15;
  const int hb2  = w * 64;

  const float4 wq4 = *(const float4*)&Wq[j*4];
  const float4 wk4 = *(const float4*)&Wk[j*4];
  const float4 wv4 = *(const float4*)&Wv[j*4];
  float wqp[4], wkp[4], wvp[4];
  #pragma unroll
  for (int d = 0; d < 4; ++d) {
    const int idx = l2 ^ d;
    wqp[d] = sel4(wq4, idx);
    wkp[d] = sel4(wk4, idx);
    wvp[d] = sel4(wv4, idx);
  }
  const float cw0 = conv_w[j],     cw1 = conv_w[256+j];
  const float cw2 = conv_w[512+j], cw3 = conv_w[768+j];
  const float cb  = conv_b[j];

  float p1 = 0.f, p2 = 0.f, p3 = 0.f;
  #pragma unroll
  for (int t = 0; t < 16; ++t) {
    const float m = bf2f(xm_ws[(rbase + t*1024)*256 + j]);
    const float pre = cw0*p3 + cw1*p2 + cw2*p1 + cw3*m + cb;
    const float x = siluf(pre);
    p3 = p2; p2 = p1; p1 = m;
    const float x1 = __shfl_xor(x, 1), x2 = __shfl_xor(x, 2), x3 = __shfl_xor(x, 3);
    const float m1 = __shfl_xor(m, 1), m2 = __shfl_xor(m, 2), m3 = __shfl_xor(m, 3);
    const float qv = x*wqp[0] + x1*wqp[1] + x2*wqp[2] + x3*wqp[3];
    const float kv = x*wkp[0] + x1*wkp[1] + x2*wkp[2] + x3*wkp[3];
    const float vv = m*wvp[0] + m1*wvp[1] + m2*wvp[2] + m3*wvp[3];
    q_lds [t*SQ  + j] = f2bf(qv);
    k_lds [t*SQ  + j] = f2bf(kv);
    v_lds [t*SQ  + j] = f2bf(vv);
    xc_lds[t*SXC + j] = f2bf(x);
  }
  __syncthreads();

  f32x4 gacc = (f32x4){0.f, 0.f, 0.f, 0.f};
  #pragma unroll
  for (int c6 = 0; c6 < 6; ++c6) {
    const int kc = w*6 + c6;
    const ushort_t* yb = (kc < 8) ? q_lds : (kc < 16) ? k_lds : v_lds;
    const int klocal = (kc & 7)*32;
    const short8 ya = *(const short8*)&yb[lc*SQ + klocal + g*8];
    const short8 wb = *(const short8*)&wgf[(kc*64 + ln)*8];
    gacc = __builtin_amdgcn_mfma_f32_16x16x32_bf16(ya, wb, gacc, 0, 0, 0);
  }
  f32x4 qkacc = (f32x4){0.f, 0.f, 0.f, 0.f};
  {
    const short8 qa0 = *(const short8*)&q_lds[lc*SQ + hb2 + g*8];
    const short8 qa1 = *(const short8*)&q_lds[lc*SQ + hb2 + 32 + g*8];
    const short8 kb0 = *(const short8*)&k_lds[lc*SQ + hb2 + g*8];
    const short8 kb1 = *(const short8*)&k_lds[lc*SQ + hb2 + 32 + g*8];
    qkacc = __builtin_amdgcn_mfma_f32_16x16x32_bf16(qa0, kb0, qkacc, 0, 0, 0);
    qkacc = __builtin_amdgcn_mfma_f32_16x16x32_bf16(qa1, kb1, qkacc, 0, 0, 0);
  }
  if (lc < 8) {
    #pragma unroll
    for (int r = 0; r < 4; ++r)
      s_gpart[w*128 + (g*4 + r)*8 + lc] = gacc[r];
  }
  __syncthreads();

  if (tid < 128) {
    const int t = tid >> 3, n = tid & 7;
    const float s = s_gpart[t*8+n] + s_gpart[128 + t*8+n]
                  + s_gpart[256 + t*8+n] + s_gpart[384 + t*8+n];
    if (n < 4) s_ig[t*4 + n] = s + igb[n];
    else       s_lf[t*4 + (n-4)] = logsigf(s + fgb[n-4]);
  }
  __syncthreads();

  float* s_lfc = s_gpart;
  if (tid < 4) {
    float run = 0.f;
    s_lfc[tid] = 0.f;
    #pragma unroll
    for (int t = 0; t < 16; ++t) { run += s_lf[t*4 + tid]; s_lfc[(t+1)*4 + tid] = run; }
  }
  __syncthreads();

  {
    const int tcol = lc;
    const float lfc_t1 = s_lfc[(tcol+1)*4 + w];
    const float igt    = s_ig[tcol*4 + w];
    float ld[4], mloc[4];
    #pragma unroll
    for (int r = 0; r < 4; ++r) {
      const int s = g*4 + r;
      const float lfs = s_lfc[(s+1)*4 + w];
      ld[r] = (tcol <= s) ? (lfs - lfc_t1 + igt) : -INFINITY;
      mloc[r] = ld[r];
    }
    #pragma unroll
    for (int off = 1; off < 16; off <<= 1) {
      #pragma unroll
      for (int r = 0; r < 4; ++r) mloc[r] = fmaxf(mloc[r], __shfl_xor(mloc[r], off));
    }
    float cs[4], rsum[4];
    #pragma unroll
    for (int r = 0; r < 4; ++r) {
      const int s = g*4 + r;
      cs[r] = (tcol <= s) ? (qkacc[r] * 0.125f) * __expf(ld[r] - mloc[r]) : 0.f;
      rsum[r] = cs[r];
    }
    #pragma unroll
    for (int off = 1; off < 16; off <<= 1) {
      #pragma unroll
      for (int r = 0; r < 4; ++r) rsum[r] += __shfl_xor(rsum[r], off);
    }
    #pragma unroll
    for (int r = 0; r < 4; ++r) {
      const float denom = fmaxf(fabsf(rsum[r]), __expf(-mloc[r])) + 1e-6f;
      const float pv = cs[r] / denom;
      p_lds[(w*16 + g*4 + r)*36 + tcol] = f2bf(pv);
    }
  }
  __syncthreads();

  f32x4 oacc[4];
  #pragma unroll
  for (int c = 0; c < 4; ++c) oacc[c] = (f32x4){0.f, 0.f, 0.f, 0.f};
  {
    const int tb = g*8;
    short8 pa = (short8){0,0,0,0,0,0,0,0};
    if (tb < 16) {
      const short4v plo = *(const short4v*)&p_lds[(w*16 + lc)*36 + tb];
      const short4v phi = *(const short4v*)&p_lds[(w*16 + lc)*36 + tb + 4];
      pa[0]=plo[0]; pa[1]=plo[1]; pa[2]=plo[2]; pa[3]=plo[3];
      pa[4]=phi[0]; pa[5]=phi[1]; pa[6]=phi[2]; pa[7]=phi[3];
    }
    #pragma unroll
    for (int c = 0; c < 4; ++c) {
      short8 vb;
      #pragma unroll
      for (int i = 0; i < 8; ++i)
        vb[i] = (short)v_lds[((tb + i) & 15)*SQ + hb2 + c*16 + lc];
      oacc[c] = __builtin_amdgcn_mfma_f32_16x16x32_bf16(pa, vb, oacc[c], 0, 0, 0);
    }
  }

  float lnc[4], skc[4];
  #pragma unroll
  for (int c = 0; c < 4; ++c) {
    const int ch = hb2 + c*16 + lc;
    lnc[c] = lnw[ch];
    skc[c] = skipw[ch];
  }
  #pragma unroll
  for (int r = 0; r < 4; ++r) {
    const int s = g*4 + r;
    float tot = oacc[0][r] + oacc[1][r] + oacc[2][r] + oacc[3][r];
    #pragma unroll
    for (int off = 1; off < 16; off <<= 1) tot += __shfl_xor(tot, off);
    const float mu = tot * (1.f/64.f);
    float var = 0.f;
    #pragma unroll
    for (int c = 0; c < 4; ++c) { const float d = oacc[c][r] - mu; var += d*d; }
    #pragma unroll
    for (int off = 1; off < 16; off <<= 1) var += __shfl_xor(var, off);
    const float rstd = rsqrtf(var * (1.f/64.f) + 1e-5f);
    #pragma unroll
    for (int c = 0; c < 4; ++c) {
      const int ch = hb2 + c*16 + lc;
      const float hn = (oacc[c][r] - mu) * rstd * lnc[c];
      const float xcv = bf2f(xc_lds[s*SXC + ch]);
      const long long off_g = (long long)(rbase + s*1024)*256 + ch;
      const float szv = bf2f(szh[off_g]);
      szh[off_g] = f2bf((hn + skc[c]*xcv) * szv);
    }
  }
}

// ---------------------------------------------------------------------------
// Phase 3: down-projection, split-bf16 MFMA, frag-major A loads.
// ---------------------------------------------------------------------------
__global__ __launch_bounds__(256, 3)
void down_gemm(const ushort_t* __restrict__ hb,
               const ushort_t* __restrict__ wdtf,
               float* __restrict__ out)
{
  const int tid = threadIdx.x;
  const int hw0 = blockIdx.x * 128;
  const int bt  = blockIdx.z;
  const int bq  = bt >> 4, tq = bt & 15;
  const int rowbase = bt*1024 + hw0;

  const int wv = tid >> 6;
  const int wm = wv >> 1, wn = wv & 1;
  const int ln = tid & 63;
  const int lm = ln & 15;
  const int q  = ln >> 4;

  f32x4 acc[4][4];
  #pragma unroll
  for (int i = 0; i < 4; ++i)
    #pragma unroll
    for (int k = 0; k < 4; ++k) acc[i][k] = (f32x4){0.f, 0.f, 0.f, 0.f};

  #pragma unroll 2
  for (int kc = 0; kc < 256; kc += 32) {
    const int kq = kc + q*8;
    const int kcIdx = kc >> 5;
    short8 ah[4], al[4];
    #pragma unroll
    for (int mt = 0; mt < 4; ++mt) {
      const int base = ((wm*4 + mt)*8 + kcIdx)*1024;
      ah[mt] = *(const short8*)&wdtf[base + ln*8];
      al[mt] = *(const short8*)&wdtf[base + 512 + ln*8];
    }
    #pragma unroll
    for (int nt = 0; nt < 4; ++nt) {
      const int n = wn*64 + nt*16 + lm;
      const short8 bf = *(const short8*)&hb[(rowbase + n)*256 + kq];
      #pragma unroll
      for (int mt = 0; mt < 4; ++mt) {
        acc[mt][nt] = __builtin_amdgcn_mfma_f32_16x16x32_bf16(ah[mt], bf, acc[mt][nt], 0, 0, 0);
        acc[mt][nt] = __builtin_amdgcn_mfma_f32_16x16x32_bf16(al[mt], bf, acc[mt][nt], 0, 0, 0);
      }
    }
  }

  #pragma unroll
  for (int mt = 0; mt < 4; ++mt) {
    #pragma unroll
    for (int nt = 0; nt < 4; ++nt) {
      const int hw = hw0 + wn*64 + nt*16 + lm;
      #pragma unroll
      for (int r = 0; r < 4; ++r) {
        const int c = wm*64 + mt*16 + q*4 + r;
        out[((bq*128 + c)*16 + tq)*1024 + hw] = acc[mt][nt][r];
      }
    }
  }
}

// ---------------------------------------------------------------------------
extern "C" void kernel_launch(void* const* d_in, const int* in_sizes, int n_in,
                              void* d_out, int out_size, void* d_ws, size_t ws_size,
                              hipStream_t stream)
{
  const float* x      = (const float*)d_in[0];
  const float* Wup    = (const float*)d_in[1];
  const float* conv_w = (const float*)d_in[2];
  const float* conv_b = (const float*)d_in[3];
  const float* Wq     = (const float*)d_in[4];
  const float* Wk     = (const float*)d_in[5];
  const float* Wv     = (const float*)d_in[6];
  const float* igw    = (const float*)d_in[7];
  const float* igb    = (const float*)d_in[8];
  const float* fgw    = (const float*)d_in[9];
  const float* fgb    = (const float*)d_in[10];
  const float* lnw    = (const float*)d_in[11];
  const float* skipw  = (const float*)d_in[12];
  const float* Wd     = (const float*)d_in[13];
  float* out = (float*)d_out;

  // ws layout (bytes):
  //   xt_hi  @ 0          32 MB   (131072 x 128 bf16)
  //   xt_lo  @ 32 MB      32 MB
  //   xmb    @ 64 MB      64 MB   (131072 x 256 bf16)
  //   szb    @ 128 MB     64 MB   (silu(z) in, h_state out)
  //   wtf    @ 192 MB     256 KB; wdtf +128 KB; wgf +24 KB
  ushort_t* xt_hi = (ushort_t*)d_ws;
  ushort_t* xt_lo = xt_hi + 16777216;
  ushort_t* xmb   = (ushort_t*)((char*)d_ws + 67108864);
  ushort_t* szb   = (ushort_t*)((char*)d_ws + 134217728);
  ushort_t* wtf   = (ushort_t*)((char*)d_ws + 201326592);
  ushort_t* wdtf  = wtf + 131072;
  ushort_t* wgf   = wdtf + 65536;

  prep_x<<<dim3(4, 128), 256, 0, stream>>>(x, xt_hi, xt_lo);
  prep_w<<<816, 256, 0, stream>>>(Wup, Wd, igw, fgw, wtf, wdtf, wgf);
  up_gemm<<<dim3(8, 4, 128), 256, 0, stream>>>(xt_hi, xt_lo, wtf, xmb, szb);
  seq_kernel<<<8192, 256, 0, stream>>>(xmb, szb,
                                       conv_w, conv_b, Wq, Wk, Wv,
                                       wgf, igb, fgb, lnw, skipw);
  down_gemm<<<dim3(8, 1, 128), 256, 0, stream>>>(szb, wdtf, out);
}